// Round 5
// baseline (610.565 us; speedup 1.0000x reference)
//
#include <hip/hip_runtime.h>
#include <math.h>

#define NB 64
#define NN 4096
#define NF 256
#define NC 10
#define NSPLIT 16
#define CH 256            // rows per split
#define TR 16             // rows per tile
#define NT (CH / TR)      // 16 tiles
#define USLOTS 4096       // k_uniq hash slots (12-bit)

typedef const unsigned __attribute__((address_space(1)))* gas_u32;
typedef unsigned __attribute__((address_space(3)))* las_u32;

// ---------------------------------------------------------------- K1: streaming stats + transpose
// v7: T3/T4 pipeline — global_load_lds DMA staging, counted vmcnt, raw s_barrier.
//   Per 16-row tile: wave w DMAs rows 4w..4w+3 (1 KB each) into the OTHER LDS buffer
//   with per-lane global source XOR-swizzled (block l reads col-block l^rt), so the
//   linear DMA deposit realizes a swizzled layout (rule #21: linear dest + inv-swz src).
//   Then: counted s_waitcnt vmcnt(4) (prev tile landed; this tile's 4 DMAs stay in
//   flight ACROSS the barrier) + raw s_barrier — no vmcnt(0) drain in the loop.
//   Compute = two conflict-free LDS read passes over the landed tile:
//     pass A (stats): thread t reads feature t's 16 values (2-way banks), cleans,
//       accumulates s1/s2/|x|/max/nanc + per-class sums (readlane'd wave-uniform y).
//     pass B (XT write-out): 4 threads/feature read 4 rows each (2-way banks), clean
//       to canonical bits (NaN→0, -0→+0), store uint4 → 64-B segments, 16/wave-instr.
//   No ds_writes at all; no VGPR prefetch array (VGPR ~50, LDS 32 KB → 5 blocks/CU).
__global__ __launch_bounds__(256) void k_stats(const float* __restrict__ X,
                                               const int* __restrict__ Y,
                                               unsigned* __restrict__ XT,
                                               float* __restrict__ P) {
  __shared__ unsigned lbuf[2][TR * 256];  // 2 x 16 KiB = 32,768 B
  const int bi = blockIdx.x;
  const int b = bi >> 4, sp = bi & 15;
  const int t = threadIdx.x;
  const int w = t >> 6, l = t & 63;
  const int n0 = sp * CH;
  const unsigned* Xu = (const unsigned*)X;

  // Y chunk preload: lane l holds rows n0+{l, 64+l, 128+l, 192+l}
  const int y0 = Y[b * NN + n0 + l];
  const int y1 = Y[b * NN + n0 + 64 + l];
  const int y2 = Y[b * NN + n0 + 128 + l];
  const int y3 = Y[b * NN + n0 + 192 + l];

  // reader-side accumulators: thread t owns feature t
  float s1 = 0.f, s2 = 0.f, sab = 0.f, mab = 0.f, nanc = 0.f;
  float cls[NC] = {};
  const int cb = t >> 2, c2 = t & 3;

  // ---- prologue: stage tile 0 into buf 0 (4 DMA instrs per wave, 1 row each)
#pragma unroll
  for (int i = 0; i < 4; ++i) {
    const int rt = 4 * w + i;
    const unsigned* src = Xu + (((size_t)(b * NN + n0 + rt)) << 8) + ((l ^ rt) << 2);
    __builtin_amdgcn_global_load_lds((gas_u32)src, (las_u32)&lbuf[0][rt * 256], 16, 0, 0);
  }

  for (int tile = 0; tile < NT; ++tile) {
    const int cur = tile & 1;
    // ---- stage next tile into the other buffer (its old contents were consumed
    //      and released by the previous iteration's trailing barrier)
    if (tile < NT - 1) {
#pragma unroll
      for (int i = 0; i < 4; ++i) {
        const int rt = 4 * w + i;
        const unsigned* src =
            Xu + (((size_t)(b * NN + n0 + (tile + 1) * TR + rt)) << 8) + ((l ^ rt) << 2);
        __builtin_amdgcn_global_load_lds((gas_u32)src, (las_u32)&lbuf[cur ^ 1][rt * 256], 16, 0, 0);
      }
      asm volatile("s_waitcnt vmcnt(4)" ::: "memory");  // tile's 4 DMAs retired; next 4 in flight
    } else {
      asm volatile("s_waitcnt vmcnt(0)" ::: "memory");
    }
    __builtin_amdgcn_s_barrier();   // all waves' deposits for buf[cur] visible

    // ---- pass A: stats for feature t over this tile's 16 rows
    const int sel = tile >> 2;
    const int yl = (sel & 2) ? ((sel & 1) ? y3 : y2) : ((sel & 1) ? y1 : y0);
    const int lbase = (tile & 3) * TR;  // wave-uniform lane base into yl
#pragma unroll
    for (int rt = 0; rt < TR; ++rt) {
      const unsigned raw = lbuf[cur][rt * 256 + (((cb ^ rt) << 2) | c2)];
      float c = __uint_as_float(raw);
      if (c != c) { nanc += 1.f; c = 0.f; }  // nan_to_num(nan=0)
      s1 += c;
      s2 = fmaf(c, c, s2);
      const float a = fabsf(c);
      sab += a;
      mab = fmaxf(mab, a);
      const int y = __builtin_amdgcn_readlane(yl, lbase + rt);  // wave-uniform
      switch (y) {
        case 0: cls[0] += c; break; case 1: cls[1] += c; break;
        case 2: cls[2] += c; break; case 3: cls[3] += c; break;
        case 4: cls[4] += c; break; case 5: cls[5] += c; break;
        case 6: cls[6] += c; break; case 7: cls[7] += c; break;
        case 8: cls[8] += c; break; case 9: cls[9] += c; break;
        default: break;
      }
    }

    // ---- pass B: XT write-out — 4 threads/feature, 64-B segments (16 per wave-instr)
#pragma unroll
    for (int j = 0; j < 4; ++j) {
      const int idx = t + 256 * j;
      const int f = idx >> 2, rq = idx & 3;
      const int fb = f >> 2, f2 = f & 3;
      unsigned uu[4];
#pragma unroll
      for (int q = 0; q < 4; ++q) {
        const int rt = rq * 4 + q;
        const unsigned raw = lbuf[cur][rt * 256 + (((fb ^ rt) << 2) | f2)];
        const float c = __uint_as_float(raw);
        uu[q] = (c != c || c == 0.f) ? 0u : raw;  // NaN→0, -0→+0 canonical bits
      }
      uint4 o; o.x = uu[0]; o.y = uu[1]; o.z = uu[2]; o.w = uu[3];
      ((uint4*)(XT + (size_t)(b * NF + f) * NN + n0 + tile * TR))[rq] = o;
    }

    asm volatile("" ::: "memory");
    __builtin_amdgcn_s_barrier();   // all reads of buf[cur] done → safe to re-stage it
  }

  float vals[16];
  vals[0] = s1; vals[1] = s2; vals[2] = sab; vals[3] = mab; vals[4] = nanc;
#pragma unroll
  for (int c = 0; c < NC; ++c) vals[5 + c] = cls[c];
  vals[15] = 0.f;
  float4* Pv = (float4*)(P + ((size_t)(b * NSPLIT + sp) * NF + t) * 16);
  Pv[0] = *(float4*)&vals[0];
  Pv[1] = *(float4*)&vals[4];
  Pv[2] = *(float4*)&vals[8];
  Pv[3] = *(float4*)&vals[12];
}

// ---------------------------------------------------------------- K3: exact distinct count per column
// claimant-tag dedup — no table scan, no clears, no initialization.
//   Per level: (1) pending keys write-race tab[h]=key. (2) barrier; copies whose
//   readback matches write a 16-bit tag (tid*16+q) to tag[h]; losers rehash.
//   (3) barrier; tag readback == own tag → claim one distinct value.
__global__ __launch_bounds__(256) void k_uniq(const unsigned* __restrict__ XT,
                                              unsigned* __restrict__ uniq) {
  __shared__ unsigned tab[USLOTS];          // 16,384 B — value write-race table
  __shared__ unsigned short tag[USLOTS];    //  8,192 B — claimant tags
  const int t = threadIdx.x;
  const size_t base = (size_t)blockIdx.x * NN;

  const uint4* Xv = (const uint4*)(XT + base);
  uint4 kv0 = Xv[t], kv1 = Xv[256 + t], kv2 = Xv[512 + t], kv3 = Xv[768 + t];

  unsigned key[16] = {kv0.x, kv0.y, kv0.z, kv0.w, kv1.x, kv1.y, kv1.z, kv1.w,
                      kv2.x, kv2.y, kv2.z, kv2.w, kv3.x, kv3.y, kv3.z, kv3.w};
  unsigned h[16];
#pragma unroll
  for (int q = 0; q < 16; ++q) h[q] = (key[q] * 2654435761u) >> 20;  // 12 bits
  unsigned pend = 0xFFFFu;
  unsigned salt = 0x9E3779B9u;
  int cnt = 0;

  while (true) {
    // (1) value write-race (plain stores; racing word-writes resolve to one winner)
#pragma unroll
    for (int q = 0; q < 16; ++q)
      if (pend & (1u << q)) tab[h[q]] = key[q];
    __syncthreads();
    // (2) classify: matching copies stake a tag claim; losers rehash for next level
    unsigned match = 0;
#pragma unroll
    for (int q = 0; q < 16; ++q)
      if (pend & (1u << q)) {
        if (tab[h[q]] == key[q]) {
          match |= (1u << q);
          tag[h[q]] = (unsigned short)(t * 16 + q);
        } else {
          h[q] = ((key[q] ^ salt) * 2654435761u) >> 20;
        }
      }
    salt += 0x9E3779B9u;
    __syncthreads();
    // (3) claim: exactly one copy of each resolved value wins the tag race
#pragma unroll
    for (int q = 0; q < 16; ++q)
      if (match & (1u << q))
        cnt += (tag[h[q]] == (unsigned short)(t * 16 + q)) ? 1 : 0;
    pend &= ~match;
    if (__syncthreads_count(pend != 0) == 0) break;  // also orders claims vs next level
  }

  for (int off = 32; off; off >>= 1) cnt += __shfl_down(cnt, off, 64);
  // loop-exit barrier ordered all table traffic; reuse tab for cross-wave partials
  if ((t & 63) == 0) tab[t >> 6] = (unsigned)cnt;
  __syncthreads();
  if (t == 0) uniq[blockIdx.x] = tab[0] + tab[1] + tab[2] + tab[3];
}

// ---------------------------------------------------------------- K2: reduce partials → 6 stats
// also computes the per-batch class histogram: compare-chain per-thread counts +
// wave shuffle-reduce — no atomics.
__global__ __launch_bounds__(256) void k_finalize(const float* __restrict__ P,
                                                  const int* __restrict__ Y,
                                                  const unsigned* __restrict__ uniq,
                                                  float* __restrict__ stats6) {
  __shared__ float whist[4 * NC];
  const int b = blockIdx.x;          // 64 blocks == batches
  const int t = threadIdx.x;

  int cnt[NC];
#pragma unroll
  for (int c = 0; c < NC; ++c) cnt[c] = 0;
#pragma unroll
  for (int i = 0; i < 16; ++i) {
    const int y = Y[b * NN + 256 * i + t];
#pragma unroll
    for (int c = 0; c < NC; ++c) cnt[c] += (y == c) ? 1 : 0;
  }
#pragma unroll
  for (int c = 0; c < NC; ++c) {
    int v = cnt[c];
    for (int off = 32; off; off >>= 1) v += __shfl_down(v, off, 64);
    cnt[c] = v;
  }
  if ((t & 63) == 0) {
#pragma unroll
    for (int c = 0; c < NC; ++c) whist[(t >> 6) * NC + c] = (float)cnt[c];
  }
  __syncthreads();

  const int f = t;
  const int col = b * 256 + f;
  float acc[16];
#pragma unroll
  for (int i = 0; i < 16; ++i) acc[i] = 0.f;
  for (int sp = 0; sp < NSPLIT; ++sp) {
    const float4* p4 = (const float4*)(P + ((size_t)(b * NSPLIT + sp) * NF + f) * 16);
    float4 A = p4[0], B4 = p4[1], C4 = p4[2], D4 = p4[3];
    acc[0] += A.x; acc[1] += A.y; acc[2] += A.z; acc[3] = fmaxf(acc[3], A.w);
    acc[4] += B4.x; acc[5] += B4.y; acc[6] += B4.z; acc[7] += B4.w;
    acc[8] += C4.x; acc[9] += C4.y; acc[10] += C4.z; acc[11] += C4.w;
    acc[12] += D4.x; acc[13] += D4.y; acc[14] += D4.z;
  }
  const float invN = 1.f / (float)NN;
  const float mean = acc[0] * invN;
  float var = acc[1] * invN - mean * mean;
  if (var < 0.f) var = 0.f;
  const float meanabs = acc[2] * invN;
  const float maxabs = acc[3];
  const float miss = acc[4] * invN;
  const float uratio = (float)uniq[col] * invN;
  float btw = 0.f;
#pragma unroll
  for (int c = 0; c < NC; ++c) {
    const float cntc = whist[c] + whist[NC + c] + whist[2 * NC + c] + whist[3 * NC + c];
    const float m = acc[5 + c] / fmaxf(cntc, 1.f);
    const float d = m - mean;
    btw = fmaf(cntc * d, d, btw);
  }
  btw *= invN;  // counts.sum() == N
  const float target = btw / fmaxf(var, 1e-6f);
  float st[6] = {target, miss, uratio, var, meanabs, maxabs};
#pragma unroll
  for (int i = 0; i < 6; ++i)
    if (!(fabsf(st[i]) <= 3.4028235e38f)) st[i] = 0.f;  // nan_to_num(nan/±inf → 0)
#pragma unroll
  for (int i = 0; i < 6; ++i) stats6[(size_t)col * 6 + i] = st[i];
}

// ---------------------------------------------------------------- K4: MLP  gelu(stats@W1+b1)@W2+b2
__global__ __launch_bounds__(256) void k_mlp(const float* __restrict__ stats6,
                                             const float* __restrict__ W1,
                                             const float* __restrict__ b1,
                                             const float* __restrict__ W2,
                                             const float* __restrict__ b2,
                                             float* __restrict__ out) {
  __shared__ float w1s[6 * 64];
  __shared__ float b1s[64];
  __shared__ float w2s[64 * 128];
  __shared__ float b2s[128];
  __shared__ float sts[32 * 6];
  __shared__ float hs[64 * 36];  // pitch 36 keeps float4 reads 16B-aligned
  const int t = threadIdx.x;
  const int cb0 = blockIdx.x * 32;
  for (int i = t; i < 96; i += 256) ((float4*)w1s)[i] = ((const float4*)W1)[i];
  if (t < 64) b1s[t] = b1[t];
  for (int i = t; i < 2048; i += 256) ((float4*)w2s)[i] = ((const float4*)W2)[i];
  if (t < 128) b2s[t] = b2[t];
  if (t < 48) ((float4*)sts)[t] = ((const float4*)(stats6 + (size_t)cb0 * 6))[t];
  __syncthreads();

  const int k = t & 63, cg = t >> 6;
#pragma unroll
  for (int cc = 0; cc < 8; ++cc) {
    const int col = cg + 4 * cc;
    float pre = b1s[k];
#pragma unroll
    for (int s = 0; s < 6; ++s) pre = fmaf(sts[col * 6 + s], w1s[s * 64 + k], pre);
    const float h = 0.5f * pre * (1.f + erff(pre * 0.70710678118654752f));  // exact gelu
    hs[k * 36 + col] = h;
  }
  __syncthreads();

  const int j4 = (t & 31) * 4, c4 = (t >> 5) * 4;
  float4 a[4];
  const float4 bj = *(const float4*)&b2s[j4];
  a[0] = bj; a[1] = bj; a[2] = bj; a[3] = bj;
  for (int kk = 0; kk < 64; ++kk) {
    const float4 wv = *(const float4*)&w2s[kk * 128 + j4];
    const float4 hv = *(const float4*)&hs[kk * 36 + c4];
    const float hc[4] = {hv.x, hv.y, hv.z, hv.w};
#pragma unroll
    for (int ci = 0; ci < 4; ++ci) {
      a[ci].x = fmaf(hc[ci], wv.x, a[ci].x);
      a[ci].y = fmaf(hc[ci], wv.y, a[ci].y);
      a[ci].z = fmaf(hc[ci], wv.z, a[ci].z);
      a[ci].w = fmaf(hc[ci], wv.w, a[ci].w);
    }
  }
#pragma unroll
  for (int ci = 0; ci < 4; ++ci) {
    const int col = cb0 + c4 + ci;
    *(float4*)&out[(size_t)col * 128 + j4] = a[ci];
  }
}

// ---------------------------------------------------------------- launch
extern "C" void kernel_launch(void* const* d_in, const int* in_sizes, int n_in,
                              void* d_out, int out_size, void* d_ws, size_t ws_size,
                              hipStream_t stream) {
  const float* X = (const float*)d_in[0];
  const int* Y = (const int*)d_in[1];
  const float* W1 = (const float*)d_in[2];
  const float* b1 = (const float*)d_in[3];
  const float* W2 = (const float*)d_in[4];
  const float* b2 = (const float*)d_in[5];
  float* out = (float*)d_out;

  // workspace layout (~272.4 MiB)
  char* w = (char*)d_ws;
  unsigned* XT = (unsigned*)w;                          // 268,435,456 B  [B,F,N] cleaned bit patterns
  float* P = (float*)(w + 268435456ull);                //  16,777,216 B  partial stats [B,S,F,16]
  float* stats6 = (float*)(w + 285212672ull);           //     393,216 B  [16384,6]
  unsigned* uniq = (unsigned*)(w + 285608448ull);       //      65,536 B  [16384]

  k_stats<<<NB * NSPLIT, 256, 0, stream>>>(X, Y, XT, P);
  k_uniq<<<NB * NF, 256, 0, stream>>>(XT, uniq);
  k_finalize<<<NB, 256, 0, stream>>>(P, Y, uniq, stats6);
  k_mlp<<<512, 256, 0, stream>>>(stats6, W1, b1, W2, b2, out);
}